// Round 2
// baseline (1033.841 us; speedup 1.0000x reference)
//
#include <hip/hip_runtime.h>

#define NCODES 1024
#define DIM 64
#define HW 4096       // 64*64
#define CHW 262144    // 64*4096
#define NPOS 131072   // 32*64*64
#define NELEM 8388608 // 32*64*64*64
#define CHUNK 256     // codes per wave

// ws layout (bytes):
//  [0..4)        float sum of (z_q - z)^2 (atomic)
//  [256..4352)   int flags[1024]
//  [8192..12288) float cbnorm[1024]

__global__ __launch_bounds__(256) void cb_norms_kernel(
    const float* __restrict__ cb, float* __restrict__ cbnorm) {
  int j = blockIdx.x * 256 + threadIdx.x;
  if (j < NCODES) {
    const float* e = cb + j * DIM;
    float s = 0.f;
#pragma unroll
    for (int k = 0; k < DIM; ++k) s = fmaf(e[k], e[k], s);
    cbnorm[j] = s;
  }
}

template <int W>
__device__ __forceinline__ void epilogue16(const float* __restrict__ eb,
                                           const float zr[DIM],
                                           float* __restrict__ op,
                                           float& lsum) {
#pragma unroll
  for (int cc = 0; cc < 16; ++cc) {
    const int c = W * 16 + cc;  // compile-time constant index into zr
    float e = eb[c];
    float diff = e - zr[c];          // (z_q - z)
    lsum = fmaf(diff, diff, lsum);
    op[c * HW] = zr[c] + diff;       // z + (z_q - z): match reference rounding
  }
}

__global__ __launch_bounds__(256, 4) void vq_main_kernel(
    const float* __restrict__ z, const float* __restrict__ cb,
    const float* __restrict__ cbnorm, float* __restrict__ out_zq,
    float* __restrict__ out_idx, float* __restrict__ sum_ws,
    int* __restrict__ flags) {
  const int w = threadIdx.x >> 6;     // wave id = code chunk
  const int lane = threadIdx.x & 63;  // position within block
  const int n = blockIdx.x * 64 + lane;
  const int b = n >> 12;
  const int hw = n & 4095;
  const float* zp = z + b * CHW + hw;

  float zr[DIM];
#pragma unroll
  for (int c = 0; c < DIM; ++c) zr[c] = zp[c * HW];

  // Same accumulation order as the exact-matching round-1 kernel.
  float A = 0.f;
#pragma unroll
  for (int c = 0; c < DIM; ++c) A = fmaf(zr[c], zr[c], A);

  const int j0 = w * CHUNK;
  float best = 3.4e38f;
  int bestj = j0;
  for (int jj = 0; jj < CHUNK; ++jj) {
    const int j = j0 + jj;
    const float* ej = cb + j * DIM;  // wave-uniform -> scalar loads
    float d0 = 0.f, d1 = 0.f, d2 = 0.f, d3 = 0.f;
#pragma unroll
    for (int k = 0; k < DIM; k += 4) {
      d0 = fmaf(zr[k + 0], ej[k + 0], d0);
      d1 = fmaf(zr[k + 1], ej[k + 1], d1);
      d2 = fmaf(zr[k + 2], ej[k + 2], d2);
      d3 = fmaf(zr[k + 3], ej[k + 3], d3);
    }
    float dot = (d0 + d1) + (d2 + d3);
    float dist = (A + cbnorm[j]) - 2.0f * dot;
    if (dist < best) { best = dist; bestj = j; }
  }

  // Combine the 4 chunks: packed (dist_bits<<32)|idx, min == first global min.
  __shared__ unsigned long long keys[4][64];
  unsigned long long mykey =
      ((unsigned long long)__float_as_uint(best) << 32) | (unsigned)bestj;
  keys[w][lane] = mykey;
  __syncthreads();
  unsigned long long k0 = keys[0][lane];
  unsigned long long k1 = keys[1][lane];
  unsigned long long k2 = keys[2][lane];
  unsigned long long k3 = keys[3][lane];
  unsigned long long ka = k0 < k1 ? k0 : k1;
  unsigned long long kb = k2 < k3 ? k2 : k3;
  unsigned long long kmin = ka < kb ? ka : kb;
  const int bj = (int)(kmin & 0xFFFFFFFFull);

  // Distributed epilogue: wave w writes channels [16w, 16w+16).
  const float* eb = cb + bj * DIM;
  float* op = out_zq + b * CHW + hw;
  float lsum = 0.f;
  if (w == 0)      epilogue16<0>(eb, zr, op, lsum);
  else if (w == 1) epilogue16<1>(eb, zr, op, lsum);
  else if (w == 2) epilogue16<2>(eb, zr, op, lsum);
  else             epilogue16<3>(eb, zr, op, lsum);

  if (w == 0) {
    out_idx[n] = (float)bj;
    flags[bj] = 1;
  }

  // Block reduction of lsum
  for (int off = 32; off; off >>= 1) lsum += __shfl_down(lsum, off, 64);
  __shared__ float wsum[4];
  if (lane == 0) wsum[w] = lsum;
  __syncthreads();
  if (threadIdx.x == 0) {
    atomicAdd(sum_ws, wsum[0] + wsum[1] + wsum[2] + wsum[3]);
  }
}

__global__ __launch_bounds__(1024) void vq_finalize_kernel(
    const int* __restrict__ flags, const float* __restrict__ sum_ws,
    float* __restrict__ out_scalars) {
  __shared__ int cnt[16];
  int t = threadIdx.x;
  int f = flags[t];
  for (int off = 32; off; off >>= 1) f += __shfl_down(f, off, 64);
  int lane = t & 63, wid = t >> 6;
  if (lane == 0) cnt[wid] = f;
  __syncthreads();
  if (t == 0) {
    int c = 0;
#pragma unroll
    for (int i = 0; i < 16; ++i) c += cnt[i];
    out_scalars[0] = 1.25f * (*sum_ws) / (float)NELEM;  // vq_loss
    out_scalars[1] = (float)c / (float)NCODES;          // usage
  }
}

extern "C" void kernel_launch(void* const* d_in, const int* in_sizes, int n_in,
                              void* d_out, int out_size, void* d_ws, size_t ws_size,
                              hipStream_t stream) {
  const float* z = (const float*)d_in[0];
  const float* cb = (const float*)d_in[1];
  float* out = (float*)d_out;

  float* sum_ws = (float*)d_ws;
  int* flags = (int*)((char*)d_ws + 256);
  float* cbnorm = (float*)((char*)d_ws + 8192);

  hipMemsetAsync(d_ws, 0, 8192, stream);  // zero sum + flags
  cb_norms_kernel<<<4, 256, 0, stream>>>(cb, cbnorm);
  vq_main_kernel<<<NPOS / 64, 256, 0, stream>>>(
      z, cb, cbnorm, out, out + NELEM + 2, sum_ws, flags);
  vq_finalize_kernel<<<1, NCODES, 0, stream>>>(flags, sum_ws, out + NELEM);
}

// Round 6
// 333.500 us; speedup vs baseline: 3.1000x; 3.1000x over previous
//
#include <hip/hip_runtime.h>

#define NCODES 1024
#define DIM 64
#define HW 4096       // 64*64
#define CHW 262144    // 64*4096
#define NPOS 131072   // 32*64*64
#define NELEM 8388608 // 32*64*64*64
#define CHUNK 256     // codes per wave

// ws layout (bytes):
//  [0..4)        float sum of (z_q - z)^2 (atomic)
//  [256..4352)   int flags[1024]
//  [8192..12288) float cbnorm[1024]

__global__ __launch_bounds__(256) void cb_norms_kernel(
    const float* __restrict__ cb, float* __restrict__ cbnorm) {
  int j = blockIdx.x * 256 + threadIdx.x;
  if (j < NCODES) {
    const float* e = cb + j * DIM;
    float s = 0.f;
#pragma unroll
    for (int k = 0; k < DIM; ++k) s = fmaf(e[k], e[k], s);
    cbnorm[j] = s;
  }
}

template <int W>
__device__ __forceinline__ void epilogue16(const float* __restrict__ eb,
                                           const float zr[DIM],
                                           float* __restrict__ op,
                                           float& lsum) {
#pragma unroll
  for (int cc = 0; cc < 16; ++cc) {
    const int c = W * 16 + cc;  // compile-time constant index into zr
    float e = eb[c];
    float diff = e - zr[c];          // (z_q - z)
    lsum = fmaf(diff, diff, lsum);
    op[c * HW] = zr[c] + diff;       // z + (z_q - z): match reference rounding
  }
}

__global__ __launch_bounds__(256, 2) void vq_main_kernel(
    const float* __restrict__ z, const float* __restrict__ cb,
    const float* __restrict__ cbnorm, float* __restrict__ out_zq,
    float* __restrict__ out_idx, float* __restrict__ sum_ws,
    int* __restrict__ flags) {
  const int w = threadIdx.x >> 6;     // wave id = code chunk
  const int lane = threadIdx.x & 63;  // position within block
  const int n = blockIdx.x * 64 + lane;
  const int b = n >> 12;
  const int hw = n & 4095;
  const float* zp = z + b * CHW + hw;

  float zr[DIM];
#pragma unroll
  for (int c = 0; c < DIM; ++c) zr[c] = zp[c * HW];

  // Same accumulation order as the exact-matching round-1 kernel.
  float A = 0.f;
#pragma unroll
  for (int c = 0; c < DIM; ++c) A = fmaf(zr[c], zr[c], A);

  // readfirstlane -> SGPR: compiler-provably wave-uniform chunk base, so the
  // codebook stream stays on the scalar-load path (round-2 lesson).
  const int j0 = __builtin_amdgcn_readfirstlane(w * CHUNK);

  float best = 3.4e38f;
  int bestj = j0;
  for (int jj = 0; jj < CHUNK; ++jj) {
    const int j = j0 + jj;
    const float* ej = cb + j * DIM;  // wave-uniform -> scalar loads
    float d0 = 0.f, d1 = 0.f, d2 = 0.f, d3 = 0.f;
#pragma unroll
    for (int k = 0; k < DIM; k += 4) {
      d0 = fmaf(zr[k + 0], ej[k + 0], d0);
      d1 = fmaf(zr[k + 1], ej[k + 1], d1);
      d2 = fmaf(zr[k + 2], ej[k + 2], d2);
      d3 = fmaf(zr[k + 3], ej[k + 3], d3);
    }
    float dot = (d0 + d1) + (d2 + d3);
    float dist = (A + cbnorm[j]) - 2.0f * dot;
    if (dist < best) { best = dist; bestj = j; }
  }

  // Combine the 4 chunks: packed (dist_bits<<32)|idx, min == first global min.
  __shared__ unsigned long long keys[4][64];
  unsigned long long mykey =
      ((unsigned long long)__float_as_uint(best) << 32) | (unsigned)bestj;
  keys[w][lane] = mykey;
  __syncthreads();
  unsigned long long k0 = keys[0][lane];
  unsigned long long k1 = keys[1][lane];
  unsigned long long k2 = keys[2][lane];
  unsigned long long k3 = keys[3][lane];
  unsigned long long ka = k0 < k1 ? k0 : k1;
  unsigned long long kb = k2 < k3 ? k2 : k3;
  unsigned long long kmin = ka < kb ? ka : kb;
  const int bj = (int)(kmin & 0xFFFFFFFFull);

  // Distributed epilogue: wave w writes channels [16w, 16w+16).
  const float* eb = cb + bj * DIM;
  float* op = out_zq + b * CHW + hw;
  float lsum = 0.f;
  if (w == 0)      epilogue16<0>(eb, zr, op, lsum);
  else if (w == 1) epilogue16<1>(eb, zr, op, lsum);
  else if (w == 2) epilogue16<2>(eb, zr, op, lsum);
  else             epilogue16<3>(eb, zr, op, lsum);

  if (w == 0) {
    out_idx[n] = (float)bj;
    flags[bj] = 1;
  }

  // Block reduction of lsum
  for (int off = 32; off; off >>= 1) lsum += __shfl_down(lsum, off, 64);
  __shared__ float wsum[4];
  if (lane == 0) wsum[w] = lsum;
  __syncthreads();
  if (threadIdx.x == 0) {
    atomicAdd(sum_ws, wsum[0] + wsum[1] + wsum[2] + wsum[3]);
  }
}

__global__ __launch_bounds__(1024) void vq_finalize_kernel(
    const int* __restrict__ flags, const float* __restrict__ sum_ws,
    float* __restrict__ out_scalars) {
  __shared__ int cnt[16];
  int t = threadIdx.x;
  int f = flags[t];
  for (int off = 32; off; off >>= 1) f += __shfl_down(f, off, 64);
  int lane = t & 63, wid = t >> 6;
  if (lane == 0) cnt[wid] = f;
  __syncthreads();
  if (t == 0) {
    int c = 0;
#pragma unroll
    for (int i = 0; i < 16; ++i) c += cnt[i];
    out_scalars[0] = 1.25f * (*sum_ws) / (float)NELEM;  // vq_loss
    out_scalars[1] = (float)c / (float)NCODES;          // usage
  }
}

extern "C" void kernel_launch(void* const* d_in, const int* in_sizes, int n_in,
                              void* d_out, int out_size, void* d_ws, size_t ws_size,
                              hipStream_t stream) {
  const float* z = (const float*)d_in[0];
  const float* cb = (const float*)d_in[1];
  float* out = (float*)d_out;

  float* sum_ws = (float*)d_ws;
  int* flags = (int*)((char*)d_ws + 256);
  float* cbnorm = (float*)((char*)d_ws + 8192);

  hipMemsetAsync(d_ws, 0, 8192, stream);  // zero sum + flags
  cb_norms_kernel<<<4, 256, 0, stream>>>(cb, cbnorm);
  vq_main_kernel<<<NPOS / 64, 256, 0, stream>>>(
      z, cb, cbnorm, out, out + NELEM + 2, sum_ws, flags);
  vq_finalize_kernel<<<1, NCODES, 0, stream>>>(flags, sum_ws, out + NELEM);
}